// Round 5
// baseline (284.719 us; speedup 1.0000x reference)
//
#include <hip/hip_runtime.h>
#include <math.h>

// Problem constants
#define NN 4096      // nodes
#define NE 65536     // edges
#define LL 64        // latent dims
#define KK 256       // kernel dims
#define ED 6         // edge dims
#define MAXSUPER 6144   // sum ceil(deg/32) <= (65536 + 31*4096)/32 = 6016; 6144 = 384*16

typedef __bf16 bf16_t;
typedef __attribute__((ext_vector_type(4))) __bf16 bf16x4;
typedef __attribute__((ext_vector_type(8))) __bf16 bf16x8;
typedef __attribute__((ext_vector_type(4))) float f32x4;
typedef __attribute__((ext_vector_type(16))) float f32x16;

// workspace layout (bytes)
#define OFF_CNT    ((size_t)0)           // 16384
#define OFF_DESC   ((size_t)16384)       // 8192*16 = 131072 (>= MAXSUPER*16)
#define OFF_AGG0   ((size_t)147456)      // 1 MB
#define OFF_AGG1   ((size_t)1196032)     // 1 MB
#define ZERO_BYTES ((size_t)2244608)
#define OFF_CURSOR ((size_t)2244608)     // 16384
#define OFF_DSTS   ((size_t)2260992)     // 65536*4 = 262144 (region has 512K)
#define OFF_W2R    ((size_t)2785280)     // 131072
#define OFF_W3RR   ((size_t)2916352)     // 2097152
#define OFF_Q0     ((size_t)5013504)     // 1 MB
#define OFF_Q1     ((size_t)6062080)     // 1 MB
#define OFF_X1F    ((size_t)7110656)     // 1 MB
#define OFF_X0BF   ((size_t)8159232)     // 512 KB
#define OFF_X1BF   ((size_t)8683520)     // 512 KB
#define OFF_H      ((size_t)9207808)     // 32 MB; a1 ALIASES h (in-place mlp2); SORTED order
// NOTE: P is GONE — computed on the fly in LDS inside k_fagg (R11 fusion).

__device__ __forceinline__ float gelu_f(float x) {
    return 0.5f * x * (1.0f + erff(x * 0.7071067811865476f));
}
__device__ __forceinline__ bf16_t f2bf(float x) { return (bf16_t)x; }

// ---- 1. histogram of src degrees ----
__global__ void k_hist(const int* __restrict__ ei, int* __restrict__ cnt) {
    int e = blockIdx.x * 256 + threadIdx.x;
    atomicAdd(&cnt[ei[e]], 1);
}

// ---- 2. single-block scan: cursors + 32-edge superchunk descriptors ----
__global__ void k_scan(const int* __restrict__ cnt, int* __restrict__ cursor,
                       int4* __restrict__ descs) {
    __shared__ int pd[1024], pc[1024];
    int t = threadIdx.x;
    int deg[4]; int sd = 0, sc = 0;
#pragma unroll
    for (int j = 0; j < 4; j++) {
        deg[j] = cnt[t * 4 + j];
        sd += deg[j];
        sc += (deg[j] + 31) >> 5;
    }
    pd[t] = sd; pc[t] = sc;
    __syncthreads();
    for (int off = 1; off < 1024; off <<= 1) {
        int vd = 0, vc = 0;
        if (t >= off) { vd = pd[t - off]; vc = pc[t - off]; }
        __syncthreads();
        pd[t] += vd; pc[t] += vc;
        __syncthreads();
    }
    int rd = (t > 0) ? pd[t - 1] : 0;
    int rc = (t > 0) ? pc[t - 1] : 0;
    for (int j = 0; j < 4; j++) {
        int v = t * 4 + j, d = deg[j];
        cursor[v] = rd;
        int nch = (d + 31) >> 5;
        for (int c = 0; c < nch; c++) {
            int rem = d - c * 32;
            descs[rc + c] = make_int4(v, rd + c * 32, rem < 32 ? rem : 32, 0);
        }
        rc += nch; rd += d;
    }
}

// ---- 3. fused independent pre-work ----
// blocks [0,256): prep W3rr | [256,512): prep W2r
// [512,1536): mlp1 WITH fused scatter (output lands in SORTED edge order)
// [1536,2560): node0
__global__ void __launch_bounds__(256) k_fuse3(
        const int* __restrict__ ei, int* __restrict__ cursor, int* __restrict__ dsts,
        const float* __restrict__ W3, bf16_t* __restrict__ W3rr,
        const float* __restrict__ W2, bf16_t* __restrict__ W2r,
        const float* __restrict__ attr, const float* __restrict__ W1,
        const float* __restrict__ b1, bf16_t* __restrict__ a1,
        const float* __restrict__ x, const float* __restrict__ b3,
        bf16_t* __restrict__ xbf, float* __restrict__ Q) {
    __shared__ float smem[4096];
    int bid = blockIdx.x, tid = threadIdx.x;
    if (bid < 256) {
        // ---- prep W3 (coalesced, one k-slice per block) ----
        // s(k,o) = ((k>>4)*2+(o>>5))*512 + (((k>>3)&1)*32+(o&31))*8 + (k&7)
        // f(s,i) = (s>>4)*1024 + (i>>5)*512 + ((i>>3)&3)*128 + (s&15)*8 + (i&7)
        int k0 = bid;
        for (int idx = tid; idx < 4096; idx += 256)
            smem[idx] = W3[(size_t)k0 * 4096 + idx];
        __syncthreads();
        int sbase = (2 * (k0 >> 4)) * 512 + (((k0 >> 3) & 1) * 32) * 8 + (k0 & 7);
#pragma unroll
        for (int m = 0; m < 2; m++) {
            int w = m * 256 + tid;       // 0..511
            int o = w >> 3, ib = w & 7;
            int s = sbase + (o >> 5) * 512 + (o & 31) * 8;
            int f = (s >> 4) * 1024 + (ib >> 2) * 512 + (ib & 3) * 128 + (s & 15) * 8;
            bf16x8 pk;
#pragma unroll
            for (int j = 0; j < 8; j++) pk[j] = f2bf(smem[(ib * 8 + j) * 64 + o]);
            *(bf16x8*)(W3rr + f) = pk;
        }
    } else if (bid < 512) {
        // ---- prep W2r ----
        int t = (bid - 256) * 256 + tid;
        int kk = t >> 13, nn = (t >> 9) & 15, lane = (t >> 3) & 63, j = t & 7;
        int k = kk * 32 + (lane >> 4) * 8 + j;
        int n = nn * 16 + (lane & 15);
        W2r[t] = f2bf(W2[k * 256 + n]);
    } else if (bid < 1536) {
        // ---- mlp1 + scatter: write gelu(attr@W1+b1) to SORTED position ----
        float* sa = smem;                     // 384 floats
        int* spos = (int*)(smem + 512);       // 64 ints
        int e0 = (bid - 512) * 64;
        for (int i = tid; i < 64 * ED; i += 256) sa[i] = attr[(size_t)e0 * ED + i];
        if (tid < 64) {
            int e = e0 + tid;
            int s = ei[e], d = ei[NE + e];
            int p = atomicAdd(&cursor[s], 1);
            dsts[p] = d;
            spos[tid] = p;
        }
        int col4 = (tid & 63) * 4;
        float w[ED][4], bb[4];
#pragma unroll
        for (int j = 0; j < ED; j++)
#pragma unroll
            for (int c = 0; c < 4; c++) w[j][c] = W1[j * 256 + col4 + c];
#pragma unroll
        for (int c = 0; c < 4; c++) bb[c] = b1[col4 + c];
        __syncthreads();
        int esub = tid >> 6;
#pragma unroll 1
        for (int eg = 0; eg < 16; eg++) {
            int el = eg * 4 + esub;
            int pos = spos[el];
            float av[ED];
#pragma unroll
            for (int j = 0; j < ED; j++) av[j] = sa[el * ED + j];
            bf16x4 ov;
#pragma unroll
            for (int c = 0; c < 4; c++) {
                float acc = bb[c];
#pragma unroll
                for (int j = 0; j < ED; j++) acc += av[j] * w[j][c];
                ov[c] = f2bf(gelu_f(acc));
            }
            *(bf16x4*)(a1 + (size_t)pos * 256 + col4) = ov;
        }
    } else {
        // ---- node0: xbf + Q, 4 nodes/block ----
        int v = (bid - 1536) * 4 + (tid >> 6);
        int o = tid & 63;
        float xv = x[v * 64 + o];
        smem[tid] = xv;
        xbf[v * 64 + o] = f2bf(xv);
        __syncthreads();
        const float* sx = smem + (tid >> 6) * 64;
        float q = 0.0f;
#pragma unroll 8
        for (int i = 0; i < 64; i++) q += sx[i] * b3[i * 64 + o];
        Q[v * 64 + o] = q;
    }
}

// ---- MLP layer 2: h = gelu(a1 @ W2 + b2), LDS-staged, in-place ----
// a1 aliases h (in-place slab transform) -> NO __restrict__ on a1/h.
// Safe: every h-store in a wave depends via wave-synchronous MFMA on ALL that
// wave's a1-loads (rows [base,base+32)); waves touch disjoint row slabs.
__global__ void __launch_bounds__(256) k_mlp2(const bf16_t* a1,
                                              const bf16_t* __restrict__ W2r,
                                              const float* __restrict__ b2,
                                              bf16_t* h) {
    __shared__ bf16_t sB[16384];
    int tid = threadIdx.x;
    int wave = tid >> 6, lane = tid & 63, col = lane & 15, quad = lane >> 4;
    int base = blockIdx.x * 128 + wave * 32;
    bf16x8 a[2][8];
#pragma unroll
    for (int t = 0; t < 2; t++) {
        const bf16_t* arow = a1 + (size_t)(base + t * 16 + col) * 256;
#pragma unroll
        for (int kk = 0; kk < 8; kk++)
            a[t][kk] = *(const bf16x8*)(arow + kk * 32 + quad * 8);
    }
#pragma unroll 1
    for (int p = 0; p < 4; p++) {
#pragma unroll
        for (int it = 0; it < 8; it++) {
            int c = it * 256 + tid;
            int fl = c >> 6;
            int e = (c & 63) * 8;
            int kk = fl >> 2, nnl = fl & 3;
            *(bf16x8*)(sB + fl * 512 + e) =
                *(const bf16x8*)(W2r + (size_t)(kk * 16 + p * 4 + nnl) * 512 + e);
        }
        __syncthreads();
#pragma unroll
        for (int nnl = 0; nnl < 4; nnl++) {
            f32x4 acc0, acc1;
#pragma unroll
            for (int r = 0; r < 4; r++) { acc0[r] = 0.0f; acc1[r] = 0.0f; }
#pragma unroll
            for (int kk = 0; kk < 8; kk++) {
                bf16x8 b = *(const bf16x8*)(sB + (kk * 4 + nnl) * 512 + lane * 8);
                acc0 = __builtin_amdgcn_mfma_f32_16x16x32_bf16(a[0][kk], b, acc0, 0, 0, 0);
                acc1 = __builtin_amdgcn_mfma_f32_16x16x32_bf16(a[1][kk], b, acc1, 0, 0, 0);
            }
            int ncol = (p * 4 + nnl) * 16 + col;
            float bv = b2[ncol];
#pragma unroll
            for (int r = 0; r < 4; r++) {
                int row0 = base + quad * 4 + r;
                h[(size_t)row0 * 256 + ncol] = f2bf(gelu_f(acc0[r] + bv));
                h[(size_t)(row0 + 16) * 256 + ncol] = f2bf(gelu_f(acc1[r] + bv));
            }
        }
        __syncthreads();
    }
}

// ---- FUSED P-compute + aggregation (replaces pgemm + agg; P never in HBM) ----
// Block: 512 threads (8 waves) owns NCH=16 superchunks. Per k-tile kt (16):
//   P-phase: wave w computes strip 4kt+(w>>1), nn=(w&1)*8..+8 for ALL 16
//     slot-nodes via the verified pgemm MFMA (A=W3 frag, B=x frag); D-frags
//     written DIRECTLY to LDS Pls[strip&3][slot][s_loc], s_loc=nn*16+quad*4+r
//     (identical content to the old P[strip][v][s_loc]; the old sw transpose
//     existed only for global-store coalescing).
//   barrier; agg-phase: wave w, slots {2w,2w+1}: A = h frag (kt slice),
//     B = Pls[khalf][slot][row*8..], Pls[2+khalf][slot][row*8..]  — the old
//     seg&3 = {khalf, 2+khalf} formula, so the producer/consumer bijection is
//     inherited from the PASSING round-4 kernel. barrier.
// Epilogue: Q + __shfl + atomics, verbatim from old k_agg, per chunk.
// 264-elem row pad: writes ~4-way banked, reads 16B-aligned (528=33*16).
// No early return (barriers); empty chunks (cnt=0) are computed and their
// atomics predicated off by mm<cnt.
__global__ void __launch_bounds__(512) k_fagg(const int4* __restrict__ descs,
                                              const int* __restrict__ dsts,
                                              const bf16_t* __restrict__ xbf,
                                              const bf16_t* __restrict__ W3rr,
                                              const bf16_t* __restrict__ h,
                                              const float* __restrict__ Q,
                                              float* __restrict__ agg) {
    __shared__ __align__(16) bf16_t Pls[4][16][264];   // 33792 B
    __shared__ int sv[16], sbase[16], scnt[16];
    int tid = threadIdx.x, wave = tid >> 6, lane = tid & 63;
    if (tid < 16) {
        int4 d = descs[blockIdx.x * 16 + tid];
        sv[tid] = d.x; sbase[tid] = d.y; scnt[tid] = d.z;
    }
    __syncthreads();

    int col = lane & 15, quad = lane >> 4;      // P-phase roles
    int row = lane & 31, khalf = lane >> 5;     // agg-phase roles

    // x B-frags for all 16 slots (held for the whole kernel)
    const bf16_t* xr = xbf + (size_t)sv[col] * 64 + quad * 8;
    bf16x8 xa0 = *(const bf16x8*)xr;
    bf16x8 xa1 = *(const bf16x8*)(xr + 32);

    // per-wave agg chunk state: slots 2w, 2w+1
    int s0 = wave * 2, s1 = s0 + 1;
    int v0 = sv[s0], v1 = sv[s1];
    int cnt0 = scnt[s0], cnt1 = scnt[s1];
    bool val0 = row < cnt0, val1 = row < cnt1;
    int pos0 = sbase[s0] + (val0 ? row : 0);
    int pos1 = sbase[s1] + (val1 ? row : 0);
    int dst0 = dsts[pos0], dst1 = dsts[pos1];
    const bf16_t* h0 = h + (size_t)pos0 * 256 + khalf * 8;
    const bf16_t* h1 = h + (size_t)pos1 * 256 + khalf * 8;

    bf16x8 zero;
#pragma unroll
    for (int i = 0; i < 8; i++) zero[i] = (bf16_t)0.0f;

    f32x16 acc00, acc01, acc10, acc11;
#pragma unroll
    for (int r = 0; r < 16; r++) { acc00[r] = 0.0f; acc01[r] = 0.0f;
                                   acc10[r] = 0.0f; acc11[r] = 0.0f; }

    int pst = wave >> 1;            // strip-local 0..3
    int nn0 = (wave & 1) * 8;       // nn half

#pragma unroll 1
    for (int kt = 0; kt < 16; ++kt) {
        // ---- P-phase: strip = 4kt + pst, nn in [nn0, nn0+8) ----
        int strip = kt * 4 + pst;
        const bf16_t* wb = W3rr + (size_t)(strip * 16 + nn0) * 1024 + lane * 8;
#pragma unroll
        for (int nn = 0; nn < 8; ++nn) {
            bf16x8 b0 = *(const bf16x8*)wb;
            bf16x8 b1 = *(const bf16x8*)(wb + 512);
            wb += 1024;
            f32x4 acc;
#pragma unroll
            for (int r = 0; r < 4; r++) acc[r] = 0.0f;
            acc = __builtin_amdgcn_mfma_f32_16x16x32_bf16(b0, xa0, acc, 0, 0, 0);
            acc = __builtin_amdgcn_mfma_f32_16x16x32_bf16(b1, xa1, acc, 0, 0, 0);
            bf16x4 pk;
#pragma unroll
            for (int r = 0; r < 4; r++) pk[r] = f2bf(acc[r]);
            *(bf16x4*)(&Pls[pst][col][(nn0 + nn) * 16 + quad * 4]) = pk;
        }
        __syncthreads();
        // ---- agg-phase: 2 chunks, 4 MFMAs 32x32x16 ----
        {
            bf16x8 t0 = *(const bf16x8*)(h0 + kt * 16);
            bf16x8 af = val0 ? t0 : zero;
            bf16x8 pb0 = *(const bf16x8*)(&Pls[khalf][s0][row * 8]);
            bf16x8 pb1 = *(const bf16x8*)(&Pls[2 + khalf][s0][row * 8]);
            acc00 = __builtin_amdgcn_mfma_f32_32x32x16_bf16(af, pb0, acc00, 0, 0, 0);
            acc01 = __builtin_amdgcn_mfma_f32_32x32x16_bf16(af, pb1, acc01, 0, 0, 0);
        }
        {
            bf16x8 t1 = *(const bf16x8*)(h1 + kt * 16);
            bf16x8 af = val1 ? t1 : zero;
            bf16x8 pb0 = *(const bf16x8*)(&Pls[khalf][s1][row * 8]);
            bf16x8 pb1 = *(const bf16x8*)(&Pls[2 + khalf][s1][row * 8]);
            acc10 = __builtin_amdgcn_mfma_f32_32x32x16_bf16(af, pb0, acc10, 0, 0, 0);
            acc11 = __builtin_amdgcn_mfma_f32_32x32x16_bf16(af, pb1, acc11, 0, 0, 0);
        }
        __syncthreads();
    }

    // ---- epilogue: Q + atomics (verbatim from old k_agg) ----
    {
        float q0 = Q[v0 * 64 + row];
        float q1 = Q[v0 * 64 + 32 + row];
#pragma unroll
        for (int r = 0; r < 16; r++) {
            int mm = (r & 3) + 8 * (r >> 2) + 4 * khalf;
            int de = __shfl(dst0, mm, 64);
            if (mm < cnt0) {
                atomicAdd(&agg[(size_t)de * 64 + row], acc00[r] + q0);
                atomicAdd(&agg[(size_t)de * 64 + 32 + row], acc01[r] + q1);
            }
        }
    }
    {
        float q0 = Q[v1 * 64 + row];
        float q1 = Q[v1 * 64 + 32 + row];
#pragma unroll
        for (int r = 0; r < 16; r++) {
            int mm = (r & 3) + 8 * (r >> 2) + 4 * khalf;
            int de = __shfl(dst1, mm, 64);
            if (mm < cnt1) {
                atomicAdd(&agg[(size_t)de * 64 + row], acc10[r] + q0);
                atomicAdd(&agg[(size_t)de * 64 + 32 + row], acc11[r] + q1);
            }
        }
    }
}

// ---- combine after conv0: x1 = gelu(agg + x@Wroot + bias); also x1bf, Q1 ----
__global__ void k_combine1(const float* __restrict__ x, const float* __restrict__ agg,
                           const float* __restrict__ Wroot, const float* __restrict__ bias,
                           const float* __restrict__ b3, float* __restrict__ x1,
                           bf16_t* __restrict__ x1bf, float* __restrict__ Q1) {
    __shared__ float sx[64], sy[64];
    int v = blockIdx.x, o = threadIdx.x;
    sx[o] = x[v * 64 + o];
    __syncthreads();
    float acc = agg[v * 64 + o] + bias[o];
#pragma unroll 8
    for (int i = 0; i < 64; i++) acc += sx[i] * Wroot[i * 64 + o];
    acc = gelu_f(acc);
    x1[v * 64 + o] = acc;
    x1bf[v * 64 + o] = f2bf(acc);
    sy[o] = acc;
    __syncthreads();
    float q = 0.0f;
#pragma unroll 8
    for (int i = 0; i < 64; i++) q += sy[i] * b3[i * 64 + o];
    Q1[v * 64 + o] = q;
}

// ---- final combine: out = agg + x1@Wroot + bias ----
__global__ void k_combine2(const float* __restrict__ x1, const float* __restrict__ agg,
                           const float* __restrict__ Wroot, const float* __restrict__ bias,
                           float* __restrict__ out) {
    __shared__ float sx[64];
    int v = blockIdx.x, o = threadIdx.x;
    sx[o] = x1[v * 64 + o];
    __syncthreads();
    float acc = agg[v * 64 + o] + bias[o];
#pragma unroll 8
    for (int i = 0; i < 64; i++) acc += sx[i] * Wroot[i * 64 + o];
    out[v * 64 + o] = acc;
}

extern "C" void kernel_launch(void* const* d_in, const int* in_sizes, int n_in,
                              void* d_out, int out_size, void* d_ws, size_t ws_size,
                              hipStream_t stream) {
    const float* nodes = (const float*)d_in[0];
    const int*   ei    = (const int*)d_in[1];
    const float* attr  = (const float*)d_in[2];
    const float* W1    = (const float*)d_in[3];
    const float* b1    = (const float*)d_in[4];
    const float* W2    = (const float*)d_in[5];
    const float* b2    = (const float*)d_in[6];
    const float* W3    = (const float*)d_in[7];
    const float* b3    = (const float*)d_in[8];
    const float* Wroot = (const float*)d_in[9];
    const float* bias  = (const float*)d_in[10];
    float* out = (float*)d_out;
    char* ws = (char*)d_ws;

    int*    cnt    = (int*)(ws + OFF_CNT);
    int4*   descs  = (int4*)(ws + OFF_DESC);
    float*  agg0   = (float*)(ws + OFF_AGG0);
    float*  agg1   = (float*)(ws + OFF_AGG1);
    int*    cursor = (int*)(ws + OFF_CURSOR);
    int*    dsts   = (int*)(ws + OFF_DSTS);
    bf16_t* W2r    = (bf16_t*)(ws + OFF_W2R);
    bf16_t* W3rr   = (bf16_t*)(ws + OFF_W3RR);
    float*  Q0     = (float*)(ws + OFF_Q0);
    float*  Q1     = (float*)(ws + OFF_Q1);
    float*  x1f    = (float*)(ws + OFF_X1F);
    bf16_t* x0bf   = (bf16_t*)(ws + OFF_X0BF);
    bf16_t* x1bf   = (bf16_t*)(ws + OFF_X1BF);
    bf16_t* hbuf   = (bf16_t*)(ws + OFF_H);
    bf16_t* a1buf  = (bf16_t*)(ws + OFF_H);  // alias: mlp2 is an in-place slab transform

    hipMemsetAsync(ws, 0, ZERO_BYTES, stream);
    k_hist<<<NE / 256, 256, 0, stream>>>(ei, cnt);
    k_scan<<<1, 1024, 0, stream>>>(cnt, cursor, descs);
    k_fuse3<<<2560, 256, 0, stream>>>(ei, cursor, dsts, W3, W3rr, W2, W2r,
                                      attr, W1, b1, a1buf, nodes, b3, x0bf, Q0);
    k_mlp2<<<512, 256, 0, stream>>>(a1buf, W2r, b2, hbuf);
    // conv 0
    k_fagg<<<MAXSUPER / 16, 512, 0, stream>>>(descs, dsts, x0bf, W3rr, hbuf, Q0, agg0);
    k_combine1<<<NN, 64, 0, stream>>>(nodes, agg0, Wroot, bias, b3, x1f, x1bf, Q1);
    // conv 1
    k_fagg<<<MAXSUPER / 16, 512, 0, stream>>>(descs, dsts, x1bf, W3rr, hbuf, Q1, agg1);
    k_combine2<<<NN, 64, 0, stream>>>(x1f, agg1, Wroot, bias, out);
}